// Round 5
// baseline (671.791 us; speedup 1.0000x reference)
//
#include <hip/hip_runtime.h>
#include <stdint.h>

#define DEV __device__ __forceinline__
typedef unsigned short u16; typedef unsigned int u32; typedef unsigned long long u64;
typedef __attribute__((ext_vector_type(8))) short s8v;   // 8 x bf16 (4 VGPR)
typedef __attribute__((ext_vector_type(4))) float f4v;   // MFMA acc

#define Bb 512
#define Tt 256
#define Ff 64
#define Hh 128
#define Dd 192
#define L2E  1.4426950408889634f
#define L2E2 2.8853900817779268f

DEV u16 f2bf(float f){ u32 u = __builtin_bit_cast(u32, f); u32 r = (u + 0x7fffu + ((u>>16)&1u)) >> 16; return (u16)r; }
DEV float bf2f(u16 h){ u32 u = ((u32)h)<<16; return __builtin_bit_cast(float, u); }
DEV float sigm(float x){ return __builtin_amdgcn_rcpf(1.0f + __expf(-x)); }
// pre-scaled gate math: y = a*log2e  (sig2) or y = a*2*log2e (th2)
DEV float sig2(float y){ return __builtin_amdgcn_rcpf(1.0f + exp2f(-y)); }
DEV float th2 (float y){ return 1.0f - 2.0f*__builtin_amdgcn_rcpf(1.0f + exp2f(y)); }
DEV u32 cvtpk(float lo, float hi){ u32 d; asm("v_cvt_pk_bf16_f32 %0, %1, %2" : "=v"(d) : "v"(lo), "v"(hi)); return d; }

DEV f4v mfma16(s8v a, s8v b, f4v c){ return __builtin_amdgcn_mfma_f32_16x16x32_bf16(a, b, c, 0, 0, 0); }

// barrier that orders LDS only — does NOT drain vmcnt
DEV void barrier_lds(){ asm volatile("s_waitcnt lgkmcnt(0)\n\ts_barrier" ::: "memory"); }

// hx LDS element index for (k, col). Layout: [k/8 block][16 cols (xor-swizzled)][8 k]
DEV int hxe(int k, int c){ int blk = k>>3; return (blk*16 + (c ^ ((blk&3)<<1)))*8 + (k&7); }

DEV s8v pack8s(const float* p, float sc){
  const float4 a = *(const float4*)p; const float4 b = *(const float4*)(p+4);
  s8v r; r[0]=(short)f2bf(a.x*sc); r[1]=(short)f2bf(a.y*sc); r[2]=(short)f2bf(a.z*sc); r[3]=(short)f2bf(a.w*sc);
  r[4]=(short)f2bf(b.x*sc); r[5]=(short)f2bf(b.y*sc); r[6]=(short)f2bf(b.z*sc); r[7]=(short)f2bf(b.w*sc); return r;
}
DEV s8v pack8(const float* p){ return pack8s(p, 1.0f); }
DEV u32 pk2(float a, float b){ return (u32)f2bf(a) | ((u32)f2bf(b)<<16); }

// ---------------- prelim: last_obs, x_last, score const term ----------------
__global__ __launch_bounds__(64) void prelim_k(const float* __restrict__ x,
    const float* __restrict__ Watt, const float* __restrict__ batt,
    float* __restrict__ xlast, float* __restrict__ c0, int* __restrict__ lastobs)
{
  int b = blockIdx.x, tid = threadIdx.x;
  int cnt = 0;
  for (int it = 0; it < 4; ++it){
    int t = it*64 + tid;
    const float4* p = (const float4*)(x + ((size_t)b*Tt + t)*Ff);
    float s = 0.0f;
    #pragma unroll
    for (int q = 0; q < 16; ++q){ float4 v = p[q]; s += fabsf(v.x)+fabsf(v.y)+fabsf(v.z)+fabsf(v.w); }
    u64 m = __ballot(s != 0.0f);
    cnt += __popcll(m);
  }
  int last = cnt - 1;
  int li = (last < 0) ? (Tt-1) : last;
  float xl = x[((size_t)b*Tt + li)*Ff + tid];
  xlast[b*Ff + tid] = xl;
  float p = xl * Watt[Hh + tid];
  for (int off = 32; off; off >>= 1) p += __shfl_down(p, off);
  if (tid == 0){ c0[b] = p + batt[0]; lastobs[b] = last; }
}

// ---------------- decoder weight prep: frag-major bf16, pre-scaled by log2e ----------------
__global__ __launch_bounds__(256) void prep_wd_k(const float* __restrict__ Whhcs,
    const float* __restrict__ Wihcs, u16* __restrict__ Wd, u16* __restrict__ WdIH)
{
  int idx = blockIdx.x*256 + threadIdx.x;          // < 294912
  int j = idx & 7, lane = (idx>>3)&63;
  int f = idx>>9;                                  // < 576
  int kt = f % 6; int mtr = f/6;                   // mtr < 96
  int mt = mtr % 48, r = mtr/48;
  int ut = mt>>2, g = mt&3;
  int row = g*Dd + ut*16 + (lane&15);
  int k = kt*32 + (lane>>4)*8 + j;
  float sc = (g == 2) ? L2E2 : L2E;
  size_t src = ((size_t)r*768 + row)*Dd + k;
  Wd[idx]   = f2bf(Whhcs[src] * sc);
  WdIH[idx] = f2bf(Wihcs[src] * sc);
}

// ---------------- xw = ha @ W_ih_cs^T  (acc-init fragments, bf16; scaled via WdIH) ----------
__global__ __launch_bounds__(64) void xw_k(const u16* __restrict__ WdIH,
    const float* __restrict__ ha, u16* __restrict__ xwg)
{
  int lane = threadIdx.x, l15 = lane&15, l4 = lane>>4;
  int cg = blockIdx.x & 3, rm = blockIdx.x >> 2;   // rm < 96
  s8v af[6];
  #pragma unroll
  for (int kt=0;kt<6;++kt) af[kt] = *(const s8v*)(WdIH + (size_t)(rm*6+kt)*512 + lane*8);
  #pragma unroll
  for (int ct=0; ct<8; ++ct){
    int c = cg*128 + ct*16 + l15;
    f4v a = {0,0,0,0};
    #pragma unroll
    for (int kt=0;kt<6;++kt){
      s8v b = pack8(ha + (size_t)c*Dd + kt*32 + l4*8);
      a = mfma16(af[kt], b, a);
    }
    int bg = cg*8 + ct;
    int base = bg*24576 + rm*256 + l15*16 + l4*4;  // elements
    *(u32*)&xwg[base]   = pk2(a[0], a[1]);
    *(u32*)&xwg[base+2] = pk2(a[2], a[3]);
  }
}

// ---------------- encoder: LSTM + fused long_pred + fused online attention ----------------
__global__ __launch_bounds__(512,2) void enc_k(
    const float* __restrict__ x, const float* __restrict__ Whh, const float* __restrict__ Wih,
    const float* __restrict__ Wlong, const float* __restrict__ blong, const float* __restrict__ Watt,
    const float* __restrict__ xlast, const float* __restrict__ c0v, const int* __restrict__ lastobs,
    float* __restrict__ lp_out, float* __restrict__ ha)
{
  __shared__ __align__(16) u16 hx[2][3072];
  __shared__ float lp_lds[2][16*68];
  __shared__ float sarr[2][16];
  const int tid = threadIdx.x, wid = tid>>6, lane = tid&63, l15 = lane&15, l4 = lane>>4;
  const int b0 = blockIdx.x*16;
  const int xrow = tid>>5, xc2 = (tid&31)*2;

  // gate weight fragments, PRE-SCALED (i,f,o: log2e; g: 2log2e)
  s8v wf[4][6];
  #pragma unroll
  for (int mt = 0; mt < 4; ++mt){
    int gate = mt*Hh + wid*16 + l15;
    float sc = (mt == 2) ? L2E2 : L2E;
    #pragma unroll
    for (int kt = 0; kt < 6; ++kt){
      int k0 = kt*32 + l4*8;
      if (kt < 4) wf[mt][kt] = pack8s(Whh + (size_t)gate*Hh + k0, sc);
      else        wf[mt][kt] = pack8s(Wih + (size_t)gate*Ff + (k0 - Hh), sc);
    }
  }
  s8v wfx[6];
  {
    s8v z = {0,0,0,0,0,0,0,0};
    #pragma unroll
    for (int kt = 0; kt < 6; ++kt) wfx[kt] = z;
    if (wid < 4){
      int f = wid*16 + l15;
      #pragma unroll
      for (int kt = 0; kt < 4; ++kt) wfx[kt] = pack8(Wlong + (size_t)f*Hh + kt*32 + l4*8);
    } else if (wid == 4 && l15 == 0){
      #pragma unroll
      for (int kt = 0; kt < 4; ++kt) wfx[kt] = pack8(Watt + kt*32 + l4*8);
    }
  }
  float bl[4] = {0,0,0,0};
  if (wid < 4){
    #pragma unroll
    for (int j = 0; j < 4; ++j) bl[j] = blong[wid*16 + l4*4 + j];
  }
  const int   lastb = lastobs[b0 + l15];
  const float c0b   = c0v[b0 + l15];

  const int he0 = hxe(wid*16 + l4*4, l15);           // h write (b64)
  const int xe0 = hxe(Hh + xc2, xrow);               // x write (b32)

  // init hx[0]: h=0, x_0
  ((u64*)hx[0])[tid] = 0ull;
  {
    float2 xv = *(const float2*)(x + ((size_t)(b0+xrow)*Tt + 0)*Ff + xc2);
    *(u32*)&hx[0][xe0] = cvtpk(xv.x, xv.y);
  }
  float2 xa = *(const float2*)(x + ((size_t)(b0+xrow)*Tt + 1)*Ff + xc2);  // x_{t+1}
  float2 xb;
  __syncthreads();

  float cst[4] = {0,0,0,0}, hp[4] = {0,0,0,0}, hpp[4] = {0,0,0,0};
  float accA[4] = {0,0,0,0}, mrun = -3.0e38f, zrun = 0.0f;

#define ENC_STEP(T_, CURB_, NXTB_, XC_, XN_) { \
    const int t = (T_); \
    s8v bf[6]; \
    _Pragma("unroll") \
    for (int kt = 0; kt < 6; ++kt) \
      bf[kt] = *(const s8v*)&hx[CURB_][((kt*4 + l4)*16 + (l15 ^ (l4<<1)))*8]; \
    { int tp = t + 2; if (tp > Tt-1) tp = Tt-1; \
      XN_ = *(const float2*)(x + ((size_t)(b0+xrow)*Tt + tp)*Ff + xc2); } \
    f4v acc0 = {0,0,0,0}, acc1 = {0,0,0,0}, acc2 = {0,0,0,0}, acc3 = {0,0,0,0}, accx = {0,0,0,0}; \
    _Pragma("unroll") \
    for (int kt = 0; kt < 6; ++kt){ \
      acc0 = mfma16(wf[0][kt], bf[kt], acc0); \
      acc1 = mfma16(wf[1][kt], bf[kt], acc1); \
      acc2 = mfma16(wf[2][kt], bf[kt], acc2); \
      acc3 = mfma16(wf[3][kt], bf[kt], acc3); \
    } \
    if (wid < 5){ \
      _Pragma("unroll") \
      for (int kt = 0; kt < 6; ++kt) accx = mfma16(wfx[kt], bf[kt], accx); \
    } \
    if (wid == 4 && l4 == 0) sarr[NXTB_][l15] = accx[0] + c0b; \
    float hnew[4]; \
    _Pragma("unroll") \
    for (int j = 0; j < 4; ++j){ \
      float si = sig2(acc0[j]), sf = sig2(acc1[j]); \
      float tg = th2(acc2[j]),  so = sig2(acc3[j]); \
      float cn = sf*cst[j] + si*tg; \
      cst[j] = cn; \
      hnew[j] = so * th2(cn * L2E2); \
    } \
    if (t >= 2){ \
      float sv = sarr[CURB_][l15]; \
      if (t-2 < lastb){ \
        float mn = fmaxf(mrun, sv); \
        float sc = __expf(mrun - mn); \
        float e  = __expf(sv - mn); \
        zrun = zrun*sc + e; \
        _Pragma("unroll") \
        for (int j = 0; j < 4; ++j) accA[j] = accA[j]*sc + e*hpp[j]; \
        mrun = mn; \
      } \
    } \
    _Pragma("unroll") \
    for (int j = 0; j < 4; ++j){ hpp[j] = hp[j]; hp[j] = hnew[j]; } \
    { u32 plo = cvtpk(hnew[0], hnew[1]), phi = cvtpk(hnew[2], hnew[3]); \
      *(u64*)&hx[NXTB_][he0] = (u64)plo | ((u64)phi<<32); } \
    if (t < Tt-1) *(u32*)&hx[NXTB_][xe0] = cvtpk(XC_.x, XC_.y); \
    if (wid < 4){ \
      _Pragma("unroll") \
      for (int j = 0; j < 4; ++j) \
        lp_lds[NXTB_][l15*68 + wid*16 + l4*4 + j] = accx[j] + bl[j]; \
    } \
    if (t >= 2){ \
      float2 v; v.x = lp_lds[CURB_][xrow*68 + xc2]; v.y = lp_lds[CURB_][xrow*68 + xc2 + 1]; \
      *(float2*)(lp_out + ((size_t)(b0+xrow)*Tt + (t-2))*Ff + xc2) = v; \
    } \
    barrier_lds(); }

  for (int tp2 = 0; tp2 < 128; ++tp2){
    ENC_STEP(2*tp2,   0, 1, xa, xb)
    ENC_STEP(2*tp2+1, 1, 0, xb, xa)
  }
#undef ENC_STEP

  // epilogue (after loop: hx[0]=h_255, sarr[0]=s_254, lp_lds[0]=lp_254)
  {
    if (254 < lastb){
      float sv = sarr[0][l15];
      float mn = fmaxf(mrun, sv);
      float sc = __expf(mrun - mn);
      float e  = __expf(sv - mn);
      zrun = zrun*sc + e;
      #pragma unroll
      for (int j = 0; j < 4; ++j) accA[j] = accA[j]*sc + e*hpp[j];
      mrun = mn;
    }
    { float2 v; v.x = lp_lds[0][xrow*68 + xc2]; v.y = lp_lds[0][xrow*68 + xc2 + 1];
      *(float2*)(lp_out + ((size_t)(b0+xrow)*Tt + 254)*Ff + xc2) = v; }
    s8v bfE[4];
    #pragma unroll
    for (int kt = 0; kt < 4; ++kt)
      bfE[kt] = *(const s8v*)&hx[0][((kt*4 + l4)*16 + (l15 ^ (l4<<1)))*8];
    if (wid < 4){
      f4v accx = {0,0,0,0};
      #pragma unroll
      for (int kt = 0; kt < 4; ++kt) accx = mfma16(wfx[kt], bfE[kt], accx);
      #pragma unroll
      for (int j = 0; j < 4; ++j) lp_lds[1][l15*68 + wid*16 + l4*4 + j] = accx[j] + bl[j];
    }
    float inv = (zrun > 0.0f) ? __builtin_amdgcn_rcpf(zrun) : 0.0f;
    #pragma unroll
    for (int j = 0; j < 4; ++j)
      ha[(size_t)(b0 + l15)*Dd + wid*16 + l4*4 + j] = accA[j]*inv;
    __syncthreads();
    { float2 v; v.x = lp_lds[1][xrow*68 + xc2]; v.y = lp_lds[1][xrow*68 + xc2 + 1];
      *(float2*)(lp_out + ((size_t)(b0+xrow)*Tt + 255)*Ff + xc2) = v; }
    for (int q = tid; q < 16*Ff; q += 512){
      int r2 = q >> 6, f = q & 63;
      ha[(size_t)(b0 + r2)*Dd + Hh + f] = xlast[(b0 + r2)*Ff + f];
    }
  }
}

// ---------------- decoder v4: risk0 regs, risk1 LDS(kt0,1)+unit-tile streamed(kt2..5) -------
__global__ __launch_bounds__(256,1) void dec_k(const float* __restrict__ ha,
    const u16* __restrict__ Wd, const u16* __restrict__ xwg,
    const float* __restrict__ Wcs, const float* __restrict__ bcs, float* __restrict__ outs)
{
  __shared__ __align__(16) u16 hx[2][3072];          // 12 KB
  __shared__ __align__(16) u16 w1[48*2*512];         // 96 KB: risk1 kt0,1 frag chunks
  __shared__ __align__(16) u16 xwl[2*48*256];        // 48 KB: acc-init frags (scaled)
  __shared__ float red[2][4][16];
  const int tid = threadIdx.x, wid = tid>>6, lane = tid&63, l15 = lane&15, l4 = lane>>4;
  const int b0 = blockIdx.x*16;

  // ha -> hx[0]
  #pragma unroll
  for (int it = 0; it < 3; ++it){
    int k = it*64 + (tid>>4)*4, c = tid&15;
    float4 v = *(const float4*)(ha + (size_t)(b0+c)*Dd + k);
    int e = hxe(k, c);
    *(u32*)&hx[0][e]   = cvtpk(v.x, v.y);
    *(u32*)&hx[0][e+2] = cvtpk(v.z, v.w);
  }
  // xwl copy
  {
    const u16* src = xwg + (size_t)blockIdx.x*24576;
    #pragma unroll
    for (int i = 0; i < 12; ++i){
      int off = (i*256 + tid)*8;
      *(s8v*)&xwl[off] = *(const s8v*)(src + off);
    }
  }
  // w1 copy: dst chunk (mtg*2+kt)*512  <-  Wd[((48+mtg)*6+kt)*512]
  #pragma unroll
  for (int i = 0; i < 24; ++i){
    int off = (i*256 + tid)*8;
    int chunk = off>>9, inner = off&511;
    int mtg = chunk>>1, kt = chunk&1;
    *(s8v*)&w1[off] = *(const s8v*)(Wd + (size_t)((48+mtg)*6+kt)*512 + inner);
  }
  // risk0 weights in registers
  s8v wreg[12][6];
  #pragma unroll
  for (int m = 0; m < 12; ++m)
    #pragma unroll
    for (int kt = 0; kt < 6; ++kt)
      wreg[m][kt] = *(const s8v*)(Wd + (size_t)((wid*12+m)*6+kt)*512 + lane*8);

  float cst[3][4], wcsr0[3][4], wcsr1[3][4];
  #pragma unroll
  for (int ut = 0; ut < 3; ++ut){
    int u0 = (wid*3+ut)*16 + l4*4;
    #pragma unroll
    for (int jj = 0; jj < 4; ++jj){
      cst[ut][jj]   = ha[(size_t)(b0+l15)*Dd + u0 + jj];
      wcsr0[ut][jj] = Wcs[u0 + jj];
      wcsr1[ut][jj] = Wcs[Dd + u0 + jj];
    }
  }
  const float bc0 = bcs[0], bc1 = bcs[1];
  __syncthreads();

  const u16* wsb = Wd + (size_t)(48 + wid*12)*6*512 + lane*8;   // risk1 stream base
  s8v st[4][4];                                                  // one unit-tile of kt2..5 (64 VGPR)
#define LOADS_UT(ut_) { \
    _Pragma("unroll") for (int g_=0; g_<4; ++g_) \
      _Pragma("unroll") for (int q_=0; q_<4; ++q_) \
        st[g_][q_] = *(const s8v*)(wsb + (size_t)(((ut_)*4+g_)*6 + 2 + q_)*512); }

#define XWINIT(r_, m_, a_) { \
    int xb_ = ((r_)*48 + wid*12 + (m_))*256 + l15*16 + l4*4; \
    u64 q_ = *(const u64*)&xwl[xb_]; \
    u32 qlo_ = (u32)q_, qhi_ = (u32)(q_>>32); \
    a_[0] = __builtin_bit_cast(float, qlo_<<16); \
    a_[1] = __builtin_bit_cast(float, qlo_ & 0xffff0000u); \
    a_[2] = __builtin_bit_cast(float, qhi_<<16); \
    a_[3] = __builtin_bit_cast(float, qhi_ & 0xffff0000u); }

#define CELLS(ut_, wcs_, nxtb_, a0_, a1_, a2_, a3_) { \
    float hn[4]; \
    _Pragma("unroll") for (int j = 0; j < 4; ++j){ \
      float si = sig2(a0_[j]), sf = sig2(a1_[j]); \
      float tg = th2(a2_[j]),  so = sig2(a3_[j]); \
      float cn = sf*cst[ut_][j] + si*tg; \
      cst[ut_][j] = cn; \
      hn[j] = so * th2(cn * L2E2); \
      part += hn[j] * wcs_[ut_][j]; } \
    u32 plo_ = cvtpk(hn[0], hn[1]), phi_ = cvtpk(hn[2], hn[3]); \
    int u0_ = (wid*3+(ut_))*16 + l4*4; \
    int e0_ = (((u0_>>3)*16) + (l15 ^ (((u0_>>3)&3)<<1)))*8 + (u0_&7); \
    *(u64*)&hx[nxtb_][e0_] = (u64)plo_ | ((u64)phi_<<32); }

  for (int sp = 0; sp < 32; ++sp){
    // ---------- EVEN step s=2sp, r=0: reads hx[0], writes hx[1] ----------
    {
      s8v bf[6];
      #pragma unroll
      for (int kt = 0; kt < 6; ++kt)
        bf[kt] = *(const s8v*)&hx[0][((kt*4 + l4)*16 + (l15 ^ (l4<<1)))*8];
      float part = 0.0f;
      #pragma unroll
      for (int ut = 0; ut < 3; ++ut){
        f4v a0,a1,a2,a3;
        XWINIT(0, ut*4+0, a0); XWINIT(0, ut*4+1, a1); XWINIT(0, ut*4+2, a2); XWINIT(0, ut*4+3, a3);
        #pragma unroll
        for (int kt = 0; kt < 6; ++kt){
          a0 = mfma16(wreg[ut*4+0][kt], bf[kt], a0);
          a1 = mfma16(wreg[ut*4+1][kt], bf[kt], a1);
          a2 = mfma16(wreg[ut*4+2][kt], bf[kt], a2);
          a3 = mfma16(wreg[ut*4+3][kt], bf[kt], a3);
        }
        CELLS(ut, wcsr0, 1, a0, a1, a2, a3);
      }
      LOADS_UT(0);                       // prefetch odd-step unit-tile 0 (kt2..5)
      part += __shfl_xor(part, 16); part += __shfl_xor(part, 32);
      if (l4 == 0) red[0][wid][l15] = part;
      barrier_lds();
      if (tid < 16)
        outs[(sp*2)*Bb + b0 + tid] = sigm(red[0][0][tid]+red[0][1][tid]+red[0][2][tid]+red[0][3][tid] + bc0);
    }
    // ---------- ODD step s=2sp+1, r=1: reads hx[1], writes hx[0] ----------
    {
      s8v bf[6];
      #pragma unroll
      for (int kt = 0; kt < 6; ++kt)
        bf[kt] = *(const s8v*)&hx[1][((kt*4 + l4)*16 + (l15 ^ (l4<<1)))*8];
      float part = 0.0f;
      #pragma unroll
      for (int ut = 0; ut < 3; ++ut){
        f4v a0,a1,a2,a3;
        XWINIT(1, ut*4+0, a0); XWINIT(1, ut*4+1, a1); XWINIT(1, ut*4+2, a2); XWINIT(1, ut*4+3, a3);
        // kt 0,1 from LDS-resident w1
        #pragma unroll
        for (int kt = 0; kt < 2; ++kt){
          s8v q0 = *(const s8v*)&w1[((wid*12+ut*4+0)*2+kt)*512 + lane*8];
          s8v q1 = *(const s8v*)&w1[((wid*12+ut*4+1)*2+kt)*512 + lane*8];
          s8v q2 = *(const s8v*)&w1[((wid*12+ut*4+2)*2+kt)*512 + lane*8];
          s8v q3 = *(const s8v*)&w1[((wid*12+ut*4+3)*2+kt)*512 + lane*8];
          a0 = mfma16(q0, bf[kt], a0);
          a1 = mfma16(q1, bf[kt], a1);
          a2 = mfma16(q2, bf[kt], a2);
          a3 = mfma16(q3, bf[kt], a3);
        }
        // kt 2..5 from streamed st (loaded one unit-tile ahead)
        #pragma unroll
        for (int q = 0; q < 4; ++q){
          a0 = mfma16(st[0][q], bf[2+q], a0);
          a1 = mfma16(st[1][q], bf[2+q], a1);
          a2 = mfma16(st[2][q], bf[2+q], a2);
          a3 = mfma16(st[3][q], bf[2+q], a3);
        }
        if (ut < 2) LOADS_UT(ut+1);      // prefetch next unit-tile (covered by CELLS below)
        CELLS(ut, wcsr1, 0, a0, a1, a2, a3);
      }
      part += __shfl_xor(part, 16); part += __shfl_xor(part, 32);
      if (l4 == 0) red[1][wid][l15] = part;
      barrier_lds();
      if (tid < 16)
        outs[(sp*2+1)*Bb + b0 + tid] = sigm(red[1][0][tid]+red[1][1][tid]+red[1][2][tid]+red[1][3][tid] + bc1);
    }
  }
#undef LOADS_UT
#undef XWINIT
#undef CELLS
}

// ---------------- final softmax over 64 steps ----------------
__global__ __launch_bounds__(256) void fin_k(const float* __restrict__ outs, float* __restrict__ dout)
{
  int row = blockIdx.x*256 + threadIdx.x;
  float v[64]; float mx = -3.0e38f;
  #pragma unroll
  for (int s = 0; s < 64; ++s){ v[s] = outs[s*Bb + row]; mx = fmaxf(mx, v[s]); }
  float sum = 0.0f;
  #pragma unroll
  for (int s = 0; s < 64; ++s){ v[s] = __expf(v[s] - mx); sum += v[s]; }
  float inv = __builtin_amdgcn_rcpf(sum);
  float* p0 = dout + (size_t)Bb*Tt*Ff;
  float* p1 = p0 + Bb*32;
  #pragma unroll
  for (int j = 0; j < 32; ++j) p0[row*32 + j] = v[j]*inv;
  #pragma unroll
  for (int j = 0; j < 32; ++j) p1[row*32 + j] = v[32 + j]*inv;
}

extern "C" void kernel_launch(void* const* d_in, const int* in_sizes, int n_in,
                              void* d_out, int out_size, void* d_ws, size_t ws_size,
                              hipStream_t stream)
{
  const float* x      = (const float*)d_in[0];
  const float* Wih    = (const float*)d_in[1];
  const float* Whh    = (const float*)d_in[2];
  const float* Wlong  = (const float*)d_in[3];
  const float* blong  = (const float*)d_in[4];
  const float* Watt   = (const float*)d_in[5];
  const float* batt   = (const float*)d_in[6];
  const float* Wihcs  = (const float*)d_in[7];
  const float* Whhcs  = (const float*)d_in[8];
  const float* Wcs    = (const float*)d_in[9];
  const float* bcs    = (const float*)d_in[10];
  float* out = (float*)d_out;
  char* ws = (char*)d_ws;

  float* xlast   = (float*)ws;                   // 131072
  float* c0      = (float*)(ws + 131072);        // 2048
  int*   lastobs = (int*)  (ws + 133120);        // 2048
  float* ha      = (float*)(ws + 135168);        // 393216 -> 528384
  u16*   Wd      = (u16*)  (ws + 528384);        // 589824 -> 1118208
  u16*   WdIH    = (u16*)  (ws + 1118208);       // 589824 -> 1708032
  u16*   xwg     = (u16*)  (ws + 1708032);       // 1572864 -> 3280896
  float* outs    = (float*)(ws + 3280896);       // 131072 -> 3411968

  prep_wd_k<<<1152, 256, 0, stream>>>(Whhcs, Wihcs, Wd, WdIH);
  prelim_k<<<Bb, 64, 0, stream>>>(x, Watt, batt, xlast, c0, lastobs);
  enc_k<<<32, 512, 0, stream>>>(x, Whh, Wih, Wlong, blong, Watt, xlast, c0, lastobs, out, ha);
  xw_k<<<384, 64, 0, stream>>>(WdIH, ha, xwg);
  dec_k<<<32, 256, 0, stream>>>(ha, Wd, xwg, Wcs, bcs, outs);
  fin_k<<<2, 256, 0, stream>>>(outs, out);
}

// Round 6
// 544.108 us; speedup vs baseline: 1.2347x; 1.2347x over previous
//
#include <hip/hip_runtime.h>
#include <stdint.h>

#define DEV __device__ __forceinline__
typedef unsigned short u16; typedef unsigned int u32; typedef unsigned long long u64;
typedef __attribute__((ext_vector_type(8))) short s8v;   // 8 x bf16 (4 VGPR)
typedef __attribute__((ext_vector_type(4))) float f4v;   // MFMA acc

#define Bb 512
#define Tt 256
#define Ff 64
#define Hh 128
#define Dd 192
#define L2E  1.4426950408889634f
#define L2E2 2.8853900817779268f

DEV u16 f2bf(float f){ u32 u = __builtin_bit_cast(u32, f); u32 r = (u + 0x7fffu + ((u>>16)&1u)) >> 16; return (u16)r; }
DEV float bf2f(u16 h){ u32 u = ((u32)h)<<16; return __builtin_bit_cast(float, u); }
DEV float sigm(float x){ return __builtin_amdgcn_rcpf(1.0f + __expf(-x)); }
// native exp2 (v_exp_f32); OCML exp2f has subnormal fixup overhead
DEV float ex2(float x){ float r; asm("v_exp_f32 %0, %1" : "=v"(r) : "v"(x)); return r; }
// gate math on PRE-SCALED accumulators: i,f,o rows scaled by -log2e; g rows by +2log2e
DEV float sig2n(float y){ return __builtin_amdgcn_rcpf(1.0f + ex2(y)); }      // == sigmoid(raw)
DEV float th2 (float y){ return 1.0f - 2.0f*__builtin_amdgcn_rcpf(1.0f + ex2(y)); } // == tanh(raw)
DEV u32 cvtpk(float lo, float hi){ u32 d; asm("v_cvt_pk_bf16_f32 %0, %1, %2" : "=v"(d) : "v"(lo), "v"(hi)); return d; }

DEV f4v mfma16(s8v a, s8v b, f4v c){ return __builtin_amdgcn_mfma_f32_16x16x32_bf16(a, b, c, 0, 0, 0); }

// barrier that orders LDS only — does NOT drain vmcnt
DEV void barrier_lds(){ asm volatile("s_waitcnt lgkmcnt(0)\n\ts_barrier" ::: "memory"); }

// hx LDS element index for (k, col). Layout: [k/8 block][16 cols (xor-swizzled)][8 k]
DEV int hxe(int k, int c){ int blk = k>>3; return (blk*16 + (c ^ ((blk&3)<<1)))*8 + (k&7); }

DEV s8v pack8s(const float* p, float sc){
  const float4 a = *(const float4*)p; const float4 b = *(const float4*)(p+4);
  s8v r; r[0]=(short)f2bf(a.x*sc); r[1]=(short)f2bf(a.y*sc); r[2]=(short)f2bf(a.z*sc); r[3]=(short)f2bf(a.w*sc);
  r[4]=(short)f2bf(b.x*sc); r[5]=(short)f2bf(b.y*sc); r[6]=(short)f2bf(b.z*sc); r[7]=(short)f2bf(b.w*sc); return r;
}
DEV s8v pack8(const float* p){ return pack8s(p, 1.0f); }
DEV u32 pk2(float a, float b){ return (u32)f2bf(a) | ((u32)f2bf(b)<<16); }

// ---------------- prelim: last_obs, x_last, score const term ----------------
__global__ __launch_bounds__(64) void prelim_k(const float* __restrict__ x,
    const float* __restrict__ Watt, const float* __restrict__ batt,
    float* __restrict__ xlast, float* __restrict__ c0, int* __restrict__ lastobs)
{
  int b = blockIdx.x, tid = threadIdx.x;
  int cnt = 0;
  for (int it = 0; it < 4; ++it){
    int t = it*64 + tid;
    const float4* p = (const float4*)(x + ((size_t)b*Tt + t)*Ff);
    float s = 0.0f;
    #pragma unroll
    for (int q = 0; q < 16; ++q){ float4 v = p[q]; s += fabsf(v.x)+fabsf(v.y)+fabsf(v.z)+fabsf(v.w); }
    u64 m = __ballot(s != 0.0f);
    cnt += __popcll(m);
  }
  int last = cnt - 1;
  int li = (last < 0) ? (Tt-1) : last;
  float xl = x[((size_t)b*Tt + li)*Ff + tid];
  xlast[b*Ff + tid] = xl;
  float p = xl * Watt[Hh + tid];
  for (int off = 32; off; off >>= 1) p += __shfl_down(p, off);
  if (tid == 0){ c0[b] = p + batt[0]; lastobs[b] = last; }
}

// ---------------- decoder weight prep: frag-major bf16, sign-folded prescale ----------------
__global__ __launch_bounds__(256) void prep_wd_k(const float* __restrict__ Whhcs,
    const float* __restrict__ Wihcs, u16* __restrict__ Wd, u16* __restrict__ WdIH)
{
  int idx = blockIdx.x*256 + threadIdx.x;          // < 294912
  int j = idx & 7, lane = (idx>>3)&63;
  int f = idx>>9;                                  // < 576
  int kt = f % 6; int mtr = f/6;                   // mtr < 96
  int mt = mtr % 48, r = mtr/48;
  int ut = mt>>2, g = mt&3;
  int row = g*Dd + ut*16 + (lane&15);
  int k = kt*32 + (lane>>4)*8 + j;
  float sc = (g == 2) ? L2E2 : -L2E;
  size_t src = ((size_t)r*768 + row)*Dd + k;
  Wd[idx]   = f2bf(Whhcs[src] * sc);
  WdIH[idx] = f2bf(Wihcs[src] * sc);
}

// ---------------- xw = ha @ W_ih_cs^T  (acc-init fragments, bf16; prescaled via WdIH) -------
__global__ __launch_bounds__(64) void xw_k(const u16* __restrict__ WdIH,
    const float* __restrict__ ha, u16* __restrict__ xwg)
{
  int lane = threadIdx.x, l15 = lane&15, l4 = lane>>4;
  int cg = blockIdx.x & 3, rm = blockIdx.x >> 2;   // rm < 96
  s8v af[6];
  #pragma unroll
  for (int kt=0;kt<6;++kt) af[kt] = *(const s8v*)(WdIH + (size_t)(rm*6+kt)*512 + lane*8);
  #pragma unroll
  for (int ct=0; ct<8; ++ct){
    int c = cg*128 + ct*16 + l15;
    f4v a = {0,0,0,0};
    #pragma unroll
    for (int kt=0;kt<6;++kt){
      s8v b = pack8(ha + (size_t)c*Dd + kt*32 + l4*8);
      a = mfma16(af[kt], b, a);
    }
    int bg = cg*8 + ct;
    int base = bg*24576 + rm*256 + l15*16 + l4*4;  // elements
    *(u32*)&xwg[base]   = pk2(a[0], a[1]);
    *(u32*)&xwg[base+2] = pk2(a[2], a[3]);
  }
}

// ---------------- encoder: LSTM + fused long_pred (direct store) + online attention --------
__global__ __launch_bounds__(512)
__attribute__((amdgpu_waves_per_eu(2,2)))
void enc_k(
    const float* __restrict__ x, const float* __restrict__ Whh, const float* __restrict__ Wih,
    const float* __restrict__ Wlong, const float* __restrict__ blong, const float* __restrict__ Watt,
    const float* __restrict__ xlast, const float* __restrict__ c0v, const int* __restrict__ lastobs,
    float* __restrict__ lp_out, float* __restrict__ ha)
{
  __shared__ __align__(16) u16 hx[2][3072];
  __shared__ float sarr[2][16];
  const int tid = threadIdx.x, wid = tid>>6, lane = tid&63, l15 = lane&15, l4 = lane>>4;
  const int b0 = blockIdx.x*16;
  const int xrow = tid>>5, xc2 = (tid&31)*2;

  // gate weight fragments, sign-folded prescale (i,f,o: -log2e; g: +2log2e)
  s8v wf[4][6];
  #pragma unroll
  for (int mt = 0; mt < 4; ++mt){
    int gate = mt*Hh + wid*16 + l15;
    float sc = (mt == 2) ? L2E2 : -L2E;
    #pragma unroll
    for (int kt = 0; kt < 6; ++kt){
      int k0 = kt*32 + l4*8;
      if (kt < 4) wf[mt][kt] = pack8s(Whh + (size_t)gate*Hh + k0, sc);
      else        wf[mt][kt] = pack8s(Wih + (size_t)gate*Ff + (k0 - Hh), sc);
    }
  }
  s8v wfx[6];
  {
    s8v z = {0,0,0,0,0,0,0,0};
    #pragma unroll
    for (int kt = 0; kt < 6; ++kt) wfx[kt] = z;
    if (wid < 4){
      int f = wid*16 + l15;
      #pragma unroll
      for (int kt = 0; kt < 4; ++kt) wfx[kt] = pack8(Wlong + (size_t)f*Hh + kt*32 + l4*8);
    } else if (wid == 4 && l15 == 0){
      #pragma unroll
      for (int kt = 0; kt < 4; ++kt) wfx[kt] = pack8(Watt + kt*32 + l4*8);
    }
  }
  float bl[4] = {0,0,0,0};
  if (wid < 4){
    #pragma unroll
    for (int j = 0; j < 4; ++j) bl[j] = blong[wid*16 + l4*4 + j];
  }
  const int   lastb = lastobs[b0 + l15];
  const float c0b   = c0v[b0 + l15];

  const int he0 = hxe(wid*16 + l4*4, l15);           // h write (b64)
  const int xe0 = hxe(Hh + xc2, xrow);               // x write (b32)
  // direct lp store base: out[(b0+l15)*256 + t-1][wid*16 + l4*4 ..+3]
  float* lpb = lp_out + ((size_t)(b0+l15)*Tt)*Ff + wid*16 + l4*4;

  // init hx[0]: h=0, x_0
  ((u64*)hx[0])[tid] = 0ull;
  {
    float2 xv = *(const float2*)(x + ((size_t)(b0+xrow)*Tt + 0)*Ff + xc2);
    *(u32*)&hx[0][xe0] = cvtpk(xv.x, xv.y);
  }
  float2 xa = *(const float2*)(x + ((size_t)(b0+xrow)*Tt + 1)*Ff + xc2);  // x_{t+1}
  float2 xb;
  __syncthreads();

  float cst[4] = {0,0,0,0}, hp[4] = {0,0,0,0}, hpp[4] = {0,0,0,0};
  float accA[4] = {0,0,0,0}, mrun = -3.0e38f, zrun = 0.0f;

#define ENC_STEP(T_, CURB_, NXTB_, XC_, XN_) { \
    const int t = (T_); \
    s8v bf[6]; \
    _Pragma("unroll") \
    for (int kt = 0; kt < 6; ++kt) \
      bf[kt] = *(const s8v*)&hx[CURB_][((kt*4 + l4)*16 + (l15 ^ (l4<<1)))*8]; \
    { int tp = t + 2; if (tp > Tt-1) tp = Tt-1; \
      XN_ = *(const float2*)(x + ((size_t)(b0+xrow)*Tt + tp)*Ff + xc2); } \
    f4v acc0 = {0,0,0,0}, acc1 = {0,0,0,0}, acc2 = {0,0,0,0}, acc3 = {0,0,0,0}, accx = {0,0,0,0}; \
    _Pragma("unroll") \
    for (int kt = 0; kt < 6; ++kt){ \
      acc0 = mfma16(wf[0][kt], bf[kt], acc0); \
      acc1 = mfma16(wf[1][kt], bf[kt], acc1); \
      acc2 = mfma16(wf[2][kt], bf[kt], acc2); \
      acc3 = mfma16(wf[3][kt], bf[kt], acc3); \
    } \
    if (wid < 5){ \
      _Pragma("unroll") \
      for (int kt = 0; kt < 6; ++kt) accx = mfma16(wfx[kt], bf[kt], accx); \
    } \
    if (wid == 4 && l4 == 0) sarr[NXTB_][l15] = accx[0] + c0b; \
    float hnew[4]; \
    _Pragma("unroll") \
    for (int j = 0; j < 4; ++j){ \
      float si = sig2n(acc0[j]), sf = sig2n(acc1[j]); \
      float tg = th2(acc2[j]),   so = sig2n(acc3[j]); \
      float cn = sf*cst[j] + si*tg; \
      cst[j] = cn; \
      hnew[j] = so * th2(cn * L2E2); \
    } \
    if (t >= 2){ \
      float sv = sarr[CURB_][l15]; \
      if (t-2 < lastb){ \
        float mn = fmaxf(mrun, sv); \
        float sc = __expf(mrun - mn); \
        float e  = __expf(sv - mn); \
        zrun = zrun*sc + e; \
        _Pragma("unroll") \
        for (int j = 0; j < 4; ++j) accA[j] = accA[j]*sc + e*hpp[j]; \
        mrun = mn; \
      } \
    } \
    _Pragma("unroll") \
    for (int j = 0; j < 4; ++j){ hpp[j] = hp[j]; hp[j] = hnew[j]; } \
    { u32 plo = cvtpk(hnew[0], hnew[1]), phi = cvtpk(hnew[2], hnew[3]); \
      *(u64*)&hx[NXTB_][he0] = (u64)plo | ((u64)phi<<32); } \
    if (t < Tt-1) *(u32*)&hx[NXTB_][xe0] = cvtpk(XC_.x, XC_.y); \
    if (wid < 4 && t >= 1){ \
      float4 v; v.x = accx[0]+bl[0]; v.y = accx[1]+bl[1]; v.z = accx[2]+bl[2]; v.w = accx[3]+bl[3]; \
      *(float4*)(lpb + (size_t)(t-1)*Ff) = v; \
    } \
    barrier_lds(); }

  for (int tp2 = 0; tp2 < 128; ++tp2){
    ENC_STEP(2*tp2,   0, 1, xa, xb)
    ENC_STEP(2*tp2+1, 1, 0, xb, xa)
  }
#undef ENC_STEP

  // epilogue (hx[0]=h_255, sarr[0]=s_254)
  {
    if (254 < lastb){
      float sv = sarr[0][l15];
      float mn = fmaxf(mrun, sv);
      float sc = __expf(mrun - mn);
      float e  = __expf(sv - mn);
      zrun = zrun*sc + e;
      #pragma unroll
      for (int j = 0; j < 4; ++j) accA[j] = accA[j]*sc + e*hpp[j];
      mrun = mn;
    }
    s8v bfE[4];
    #pragma unroll
    for (int kt = 0; kt < 4; ++kt)
      bfE[kt] = *(const s8v*)&hx[0][((kt*4 + l4)*16 + (l15 ^ (l4<<1)))*8];
    if (wid < 4){
      f4v accx = {0,0,0,0};
      #pragma unroll
      for (int kt = 0; kt < 4; ++kt) accx = mfma16(wfx[kt], bfE[kt], accx);
      float4 v; v.x = accx[0]+bl[0]; v.y = accx[1]+bl[1]; v.z = accx[2]+bl[2]; v.w = accx[3]+bl[3];
      *(float4*)(lpb + (size_t)(Tt-1)*Ff) = v;
    }
    float inv = (zrun > 0.0f) ? __builtin_amdgcn_rcpf(zrun) : 0.0f;
    #pragma unroll
    for (int j = 0; j < 4; ++j)
      ha[(size_t)(b0 + l15)*Dd + wid*16 + l4*4 + j] = accA[j]*inv;
    __syncthreads();
    for (int q = tid; q < 16*Ff; q += 512){
      int r2 = q >> 6, f = q & 63;
      ha[(size_t)(b0 + r2)*Dd + Hh + f] = xlast[(b0 + r2)*Ff + f];
    }
  }
}

// ---------------- decoder: risk0 TRULY in regs (512-VGPR cap), risk1 LDS+streamed ----------
__global__ __launch_bounds__(256)
__attribute__((amdgpu_waves_per_eu(1,1)))
void dec_k(const float* __restrict__ ha,
    const u16* __restrict__ Wd, const u16* __restrict__ xwg,
    const float* __restrict__ Wcs, const float* __restrict__ bcs, float* __restrict__ outs)
{
  __shared__ __align__(16) u16 hx[2][3072];          // 12 KB
  __shared__ __align__(16) u16 w1[48*2*512];         // 96 KB: risk1 kt0,1 frag chunks
  __shared__ __align__(16) u16 xwl[2*48*256];        // 48 KB: acc-init frags (prescaled)
  __shared__ float red[2][4][16];
  const int tid = threadIdx.x, wid = tid>>6, lane = tid&63, l15 = lane&15, l4 = lane>>4;
  const int b0 = blockIdx.x*16;

  // ha -> hx[0]
  #pragma unroll
  for (int it = 0; it < 3; ++it){
    int k = it*64 + (tid>>4)*4, c = tid&15;
    float4 v = *(const float4*)(ha + (size_t)(b0+c)*Dd + k);
    int e = hxe(k, c);
    *(u32*)&hx[0][e]   = cvtpk(v.x, v.y);
    *(u32*)&hx[0][e+2] = cvtpk(v.z, v.w);
  }
  // xwl copy
  {
    const u16* src = xwg + (size_t)blockIdx.x*24576;
    #pragma unroll
    for (int i = 0; i < 12; ++i){
      int off = (i*256 + tid)*8;
      *(s8v*)&xwl[off] = *(const s8v*)(src + off);
    }
  }
  // w1 copy: dst chunk (mtg*2+kt)*512  <-  Wd[((48+mtg)*6+kt)*512]
  #pragma unroll
  for (int i = 0; i < 24; ++i){
    int off = (i*256 + tid)*8;
    int chunk = off>>9, inner = off&511;
    int mtg = chunk>>1, kt = chunk&1;
    *(s8v*)&w1[off] = *(const s8v*)(Wd + (size_t)((48+mtg)*6+kt)*512 + inner);
  }
  // risk0 weights in registers (288 VGPR — fits under the 512 cap from waves_per_eu(1,1))
  s8v wreg[12][6];
  #pragma unroll
  for (int m = 0; m < 12; ++m)
    #pragma unroll
    for (int kt = 0; kt < 6; ++kt)
      wreg[m][kt] = *(const s8v*)(Wd + (size_t)((wid*12+m)*6+kt)*512 + lane*8);

  float cst[3][4], wcsr0[3][4], wcsr1[3][4];
  #pragma unroll
  for (int ut = 0; ut < 3; ++ut){
    int u0 = (wid*3+ut)*16 + l4*4;
    #pragma unroll
    for (int jj = 0; jj < 4; ++jj){
      cst[ut][jj]   = ha[(size_t)(b0+l15)*Dd + u0 + jj];
      wcsr0[ut][jj] = Wcs[u0 + jj];
      wcsr1[ut][jj] = Wcs[Dd + u0 + jj];
    }
  }
  const float bc0 = bcs[0], bc1 = bcs[1];
  __syncthreads();

  const u16* wsb = Wd + (size_t)(48 + wid*12)*6*512 + lane*8;   // risk1 stream base
  s8v st[4][4];                                                  // one unit-tile of kt2..5
#define LOADS_UT(ut_) { \
    _Pragma("unroll") for (int g_=0; g_<4; ++g_) \
      _Pragma("unroll") for (int q_=0; q_<4; ++q_) \
        st[g_][q_] = *(const s8v*)(wsb + (size_t)(((ut_)*4+g_)*6 + 2 + q_)*512); }

#define XWINIT(r_, m_, a_) { \
    int xb_ = ((r_)*48 + wid*12 + (m_))*256 + l15*16 + l4*4; \
    u64 q_ = *(const u64*)&xwl[xb_]; \
    u32 qlo_ = (u32)q_, qhi_ = (u32)(q_>>32); \
    a_[0] = __builtin_bit_cast(float, qlo_<<16); \
    a_[1] = __builtin_bit_cast(float, qlo_ & 0xffff0000u); \
    a_[2] = __builtin_bit_cast(float, qhi_<<16); \
    a_[3] = __builtin_bit_cast(float, qhi_ & 0xffff0000u); }

#define CELLS(ut_, wcs_, nxtb_, a0_, a1_, a2_, a3_) { \
    float hn[4]; \
    _Pragma("unroll") for (int j = 0; j < 4; ++j){ \
      float si = sig2n(a0_[j]), sf = sig2n(a1_[j]); \
      float tg = th2(a2_[j]),   so = sig2n(a3_[j]); \
      float cn = sf*cst[ut_][j] + si*tg; \
      cst[ut_][j] = cn; \
      hn[j] = so * th2(cn * L2E2); \
      part += hn[j] * wcs_[ut_][j]; } \
    u32 plo_ = cvtpk(hn[0], hn[1]), phi_ = cvtpk(hn[2], hn[3]); \
    int u0_ = (wid*3+(ut_))*16 + l4*4; \
    int e0_ = (((u0_>>3)*16) + (l15 ^ (((u0_>>3)&3)<<1)))*8 + (u0_&7); \
    *(u64*)&hx[nxtb_][e0_] = (u64)plo_ | ((u64)phi_<<32); }

  for (int sp = 0; sp < 32; ++sp){
    // ---------- EVEN step s=2sp, r=0: reads hx[0], writes hx[1] ----------
    {
      s8v bf[6];
      #pragma unroll
      for (int kt = 0; kt < 6; ++kt)
        bf[kt] = *(const s8v*)&hx[0][((kt*4 + l4)*16 + (l15 ^ (l4<<1)))*8];
      LOADS_UT(0);                       // prefetch odd-step unit-tile 0 early (full-step cover)
      float part = 0.0f;
      #pragma unroll
      for (int ut = 0; ut < 3; ++ut){
        f4v a0,a1,a2,a3;
        XWINIT(0, ut*4+0, a0); XWINIT(0, ut*4+1, a1); XWINIT(0, ut*4+2, a2); XWINIT(0, ut*4+3, a3);
        #pragma unroll
        for (int kt = 0; kt < 6; ++kt){
          a0 = mfma16(wreg[ut*4+0][kt], bf[kt], a0);
          a1 = mfma16(wreg[ut*4+1][kt], bf[kt], a1);
          a2 = mfma16(wreg[ut*4+2][kt], bf[kt], a2);
          a3 = mfma16(wreg[ut*4+3][kt], bf[kt], a3);
        }
        CELLS(ut, wcsr0, 1, a0, a1, a2, a3);
      }
      part += __shfl_xor(part, 16); part += __shfl_xor(part, 32);
      if (l4 == 0) red[0][wid][l15] = part;
      barrier_lds();
      if (tid < 16)
        outs[(sp*2)*Bb + b0 + tid] = sigm(red[0][0][tid]+red[0][1][tid]+red[0][2][tid]+red[0][3][tid] + bc0);
    }
    // ---------- ODD step s=2sp+1, r=1: reads hx[1], writes hx[0] ----------
    {
      s8v bf[6];
      #pragma unroll
      for (int kt = 0; kt < 6; ++kt)
        bf[kt] = *(const s8v*)&hx[1][((kt*4 + l4)*16 + (l15 ^ (l4<<1)))*8];
      float part = 0.0f;
      #pragma unroll
      for (int ut = 0; ut < 3; ++ut){
        f4v a0,a1,a2,a3;
        XWINIT(1, ut*4+0, a0); XWINIT(1, ut*4+1, a1); XWINIT(1, ut*4+2, a2); XWINIT(1, ut*4+3, a3);
        // kt 0,1 from LDS-resident w1
        #pragma unroll
        for (int kt = 0; kt < 2; ++kt){
          s8v q0 = *(const s8v*)&w1[((wid*12+ut*4+0)*2+kt)*512 + lane*8];
          s8v q1 = *(const s8v*)&w1[((wid*12+ut*4+1)*2+kt)*512 + lane*8];
          s8v q2 = *(const s8v*)&w1[((wid*12+ut*4+2)*2+kt)*512 + lane*8];
          s8v q3 = *(const s8v*)&w1[((wid*12+ut*4+3)*2+kt)*512 + lane*8];
          a0 = mfma16(q0, bf[kt], a0);
          a1 = mfma16(q1, bf[kt], a1);
          a2 = mfma16(q2, bf[kt], a2);
          a3 = mfma16(q3, bf[kt], a3);
        }
        // kt 2..5 from streamed st (loaded one unit-tile ahead)
        #pragma unroll
        for (int q = 0; q < 4; ++q){
          a0 = mfma16(st[0][q], bf[2+q], a0);
          a1 = mfma16(st[1][q], bf[2+q], a1);
          a2 = mfma16(st[2][q], bf[2+q], a2);
          a3 = mfma16(st[3][q], bf[2+q], a3);
        }
        if (ut < 2) LOADS_UT(ut+1);      // prefetch next unit-tile (covered by CELLS)
        CELLS(ut, wcsr1, 0, a0, a1, a2, a3);
      }
      part += __shfl_xor(part, 16); part += __shfl_xor(part, 32);
      if (l4 == 0) red[1][wid][l15] = part;
      barrier_lds();
      if (tid < 16)
        outs[(sp*2+1)*Bb + b0 + tid] = sigm(red[1][0][tid]+red[1][1][tid]+red[1][2][tid]+red[1][3][tid] + bc1);
    }
  }
#undef LOADS_UT
#undef XWINIT
#undef CELLS
}

// ---------------- final softmax over 64 steps ----------------
__global__ __launch_bounds__(256) void fin_k(const float* __restrict__ outs, float* __restrict__ dout)
{
  int row = blockIdx.x*256 + threadIdx.x;
  float v[64]; float mx = -3.0e38f;
  #pragma unroll
  for (int s = 0; s < 64; ++s){ v[s] = outs[s*Bb + row]; mx = fmaxf(mx, v[s]); }
  float sum = 0.0f;
  #pragma unroll
  for (int s = 0; s < 64; ++s){ v[s] = __expf(v[s] - mx); sum += v[s]; }
  float inv = __builtin_amdgcn_rcpf(sum);
  float* p0 = dout + (size_t)Bb*Tt*Ff;
  float* p1 = p0 + Bb*32;
  #pragma unroll
  for (int j = 0; j < 32; ++j) p0[row*32 + j] = v[j]*inv;
  #pragma unroll
  for (int j = 0; j < 32; ++j) p1[row*32 + j] = v[32 + j]*inv;
}

extern "C" void kernel_launch(void* const* d_in, const int* in_sizes, int n_in,
                              void* d_out, int out_size, void* d_ws, size_t ws_size,
                              hipStream_t stream)
{
  const float* x      = (const float*)d_in[0];
  const float* Wih    = (const float*)d_in[1];
  const float* Whh    = (const float*)d_in[2];
  const float* Wlong  = (const float*)d_in[3];
  const float* blong  = (const float*)d_in[4];
  const float* Watt   = (const float*)d_in[5];
  const float* batt   = (const float*)d_in[6];
  const float* Wihcs  = (const float*)d_in[7];
  const float* Whhcs  = (const float*)d_in[8];
  const float* Wcs    = (const float*)d_in[9];
  const float* bcs    = (const float*)d_in[10];
  float* out = (float*)d_out;
  char* ws = (char*)d_ws;

  float* xlast   = (float*)ws;                   // 131072
  float* c0      = (float*)(ws + 131072);        // 2048
  int*   lastobs = (int*)  (ws + 133120);        // 2048
  float* ha      = (float*)(ws + 135168);        // 393216 -> 528384
  u16*   Wd      = (u16*)  (ws + 528384);        // 589824 -> 1118208
  u16*   WdIH    = (u16*)  (ws + 1118208);       // 589824 -> 1708032
  u16*   xwg     = (u16*)  (ws + 1708032);       // 1572864 -> 3280896
  float* outs    = (float*)(ws + 3280896);       // 131072 -> 3411968

  prep_wd_k<<<1152, 256, 0, stream>>>(Whhcs, Wihcs, Wd, WdIH);
  prelim_k<<<Bb, 64, 0, stream>>>(x, Watt, batt, xlast, c0, lastobs);
  enc_k<<<32, 512, 0, stream>>>(x, Whh, Wih, Wlong, blong, Watt, xlast, c0, lastobs, out, ha);
  xw_k<<<384, 64, 0, stream>>>(WdIH, ha, xwg);
  dec_k<<<32, 256, 0, stream>>>(ha, Wd, xwg, Wcs, bcs, outs);
  fin_k<<<2, 256, 0, stream>>>(outs, out);
}